// Round 1
// baseline (842.568 us; speedup 1.0000x reference)
//
#include <hip/hip_runtime.h>
#include <hip/hip_bf16.h>

#define B_ 32
#define H_ 768
#define K_ 65536
#define TOPK 25
#define ENDK 25
#define NBINS 65536
#define DSTR 36864   // floats per (b,g) desc segment (max group count ~33k)

// ws byte offsets
#define OFF_LQ   0
#define OFF_X1   98304
#define OFF_X2   196608
#define OFF_CNT  294912      // u32[16]: [0]=count1, [1]=pos_min
#define OFF_HIST 524288      // u32[64*65536] = 16 MB
#define OFF_DESC 17825792    // float[64*DSTR] = 9.4 MB  (total ~27.3 MB)

// x_out[b][j] = (tanh?) ( sum_e in[b][e]*w[j][e] + bias[j] )
__global__ void k_dense(const float* __restrict__ in, const float* __restrict__ w,
                        const float* __restrict__ bias, float* __restrict__ out,
                        int apply_tanh) {
    int j = blockIdx.x;       // 0..767
    int lane = threadIdx.x;   // 0..63
    float acc[B_];
#pragma unroll
    for (int b = 0; b < B_; ++b) acc[b] = 0.f;
#pragma unroll
    for (int c = 0; c < 12; ++c) {
        float wv = w[j * H_ + lane + 64 * c];
#pragma unroll
        for (int b = 0; b < B_; ++b) acc[b] += in[b * H_ + lane + 64 * c] * wv;
    }
    float bj = bias[j];
#pragma unroll
    for (int b = 0; b < B_; ++b) {
        float v = acc[b];
#pragma unroll
        for (int off = 32; off > 0; off >>= 1) v += __shfl_xor(v, off, 64);
        if (lane == b) {
            float r = v + bj;
            out[b * H_ + j] = apply_tanh ? tanhf(r) : r;
        }
    }
}

__global__ void k_norm(const float* __restrict__ x2, float* __restrict__ lq) {
    int b = blockIdx.x, lane = threadIdx.x;
    float v[12];
    float ss = 0.f;
#pragma unroll
    for (int c = 0; c < 12; ++c) {
        v[c] = x2[b * H_ + lane + 64 * c];
        ss += v[c] * v[c];
    }
#pragma unroll
    for (int off = 32; off > 0; off >>= 1) ss += __shfl_xor(ss, off, 64);
    float rn = 1.0f / sqrtf(ss);
#pragma unroll
    for (int c = 0; c < 12; ++c) lq[b * H_ + lane + 64 * c] = v[c] * rn;
}

// Fused cos_sim + histogram. 8 waves/block; wave handles 8 b-rows, 128 k's.
__global__ __launch_bounds__(512) void k_cos_hist(
    const float* __restrict__ lq, const float* __restrict__ fq,
    const int* __restrict__ labels, const int* __restrict__ lblq,
    unsigned* __restrict__ hist) {
    int lane = threadIdx.x & 63;
    int w = threadIdx.x >> 6;       // 0..7
    int bg = w & 3;                 // b-group: rows [bg*8, bg*8+8)
    int kbase = blockIdx.x * 256 + (w >> 2) * 128;
    float4 lqr[8][3];
#pragma unroll
    for (int bb = 0; bb < 8; ++bb)
#pragma unroll
        for (int c = 0; c < 3; ++c)
            lqr[bb][c] = *(const float4*)(lq + (bg * 8 + bb) * H_ + lane * 4 + 256 * c);
    int myb = bg * 8 + (lane & 7);
    int mylab = labels[myb];
#pragma unroll 2
    for (int i = 0; i < 128; ++i) {
        int k = kbase + i;
        const float* fr = fq + (size_t)k * H_;
        float4 f0 = *(const float4*)(fr + lane * 4);
        float4 f1 = *(const float4*)(fr + lane * 4 + 256);
        float4 f2 = *(const float4*)(fr + lane * 4 + 512);
        float acc[8];
#pragma unroll
        for (int bb = 0; bb < 8; ++bb) {
            acc[bb] = lqr[bb][0].x * f0.x + lqr[bb][0].y * f0.y + lqr[bb][0].z * f0.z + lqr[bb][0].w * f0.w
                    + lqr[bb][1].x * f1.x + lqr[bb][1].y * f1.y + lqr[bb][1].z * f1.z + lqr[bb][1].w * f1.w
                    + lqr[bb][2].x * f2.x + lqr[bb][2].y * f2.y + lqr[bb][2].z * f2.z + lqr[bb][2].w * f2.w;
        }
#pragma unroll
        for (int off = 1; off < 64; off <<= 1)
#pragma unroll
            for (int bb = 0; bb < 8; ++bb) acc[bb] += __shfl_xor(acc[bb], off, 64);
        int sl = lane & 7;
        float v = acc[0];
        v = (sl == 1) ? acc[1] : v;
        v = (sl == 2) ? acc[2] : v;
        v = (sl == 3) ? acc[3] : v;
        v = (sl == 4) ? acc[4] : v;
        v = (sl == 5) ? acc[5] : v;
        v = (sl == 6) ? acc[6] : v;
        v = (sl == 7) ? acc[7] : v;
        if (lane < 8) {
            int g = (mylab == lblq[k]) ? 1 : 0;
            int bin = (int)floorf((v + 0.5f) * 65536.0f);
            bin = bin < 0 ? 0 : (bin > 65535 ? 65535 : bin);
            atomicAdd(&hist[(unsigned)(((myb << 1) | g) << 16) + (unsigned)bin], 1u);
        }
    }
}

__global__ void k_count1(const int* __restrict__ lblq, unsigned* __restrict__ cnt) {
    int idx = blockIdx.x * blockDim.x + threadIdx.x;  // 64*256 = 16384 threads
    unsigned local = 0;
    for (int k = idx; k < K_; k += 16384) local += (unsigned)lblq[k];
#pragma unroll
    for (int off = 32; off > 0; off >>= 1) local += (unsigned)__shfl_xor((int)local, off, 64);
    if ((threadIdx.x & 63) == 0) atomicAdd(cnt, local);
}

__global__ void k_posmin(const int* __restrict__ labels, const unsigned* __restrict__ cnt,
                         unsigned* __restrict__ posmin) {
    int lane = threadIdx.x;
    unsigned c1 = *cnt;
    unsigned cp = 0x7fffffffu;
    if (lane < B_) cp = (labels[lane] == 1) ? c1 : ((unsigned)K_ - c1);
#pragma unroll
    for (int off = 32; off > 0; off >>= 1) {
        unsigned o = (unsigned)__shfl_xor((int)cp, off, 64);
        cp = o < cp ? o : cp;
    }
    if (lane == 0) *posmin = cp;
}

// Expand histogram (descending) into a sorted value array per (b,g) segment.
__global__ __launch_bounds__(1024) void k_expand(const unsigned* __restrict__ hist,
                                                 float* __restrict__ desc) {
    int seg = blockIdx.x;   // 0..63 = b*2+g
    int t = threadIdx.x;    // 0..1023, owns bins [t*64, t*64+64)
    const unsigned* h = hist + (size_t)seg * NBINS + t * 64;
    unsigned cnt[64];
    unsigned s = 0;
#pragma unroll
    for (int i = 0; i < 64; ++i) { cnt[i] = h[i]; s += cnt[i]; }
    __shared__ unsigned sums[1024];
    sums[t] = s;
    __syncthreads();
    for (int off = 1; off < 1024; off <<= 1) {
        unsigned u = (t >= off) ? sums[t - off] : 0u;
        __syncthreads();
        sums[t] += u;
        __syncthreads();
    }
    unsigned total = sums[1023];
    unsigned run = total - sums[t];  // elements in higher bins (= earlier descending ranks)
    float* out = desc + (size_t)seg * DSTR;
#pragma unroll
    for (int i = 63; i >= 0; --i) {
        unsigned c = cnt[i];
        float v = ((float)(t * 64 + i) + 0.5f) * (1.0f / 65536.0f) - 0.5f;
        for (unsigned jj = 0; jj < c; ++jj)
            if (run + jj < (unsigned)DSTR) out[run + jj] = v;
        run += c;
    }
}

__global__ __launch_bounds__(512) void k_write(const float* __restrict__ desc,
                                               const unsigned* __restrict__ posmin,
                                               float* __restrict__ out, int W) {
    int r = blockIdx.x;                // 0..1599
    int b = r / (TOPK + ENDK), j = r % (TOPK + ENDK);
    const float* neg = desc + (size_t)(b * 2 + 0) * DSTR;
    const float* pos = desc + (size_t)(b * 2 + 1) * DSTR;
    float* orow = out + (size_t)r * W;
    const float invT = 14.285714285714286f;  // 1/0.07
    if (threadIdx.x == 0) {
        int pm = (int)*posmin;
        float pv = (j < TOPK) ? pos[j] : pos[pm - ENDK + (j - TOPK)];
        orow[0] = pv * invT;
    }
    for (int c = 1 + threadIdx.x; c < W; c += 512) orow[c] = neg[c - 1] * invT;
}

extern "C" void kernel_launch(void* const* d_in, const int* in_sizes, int n_in,
                              void* d_out, int out_size, void* d_ws, size_t ws_size,
                              hipStream_t stream) {
    const float* q   = (const float*)d_in[0];
    const float* dw  = (const float*)d_in[1];
    const float* db  = (const float*)d_in[2];
    const float* ow  = (const float*)d_in[3];
    const float* ob  = (const float*)d_in[4];
    const int* labels = (const int*)d_in[5];
    const int* lblq   = (const int*)d_in[6];
    const float* fq   = (const float*)d_in[7];

    char* ws = (char*)d_ws;
    float* lq = (float*)(ws + OFF_LQ);
    float* x1 = (float*)(ws + OFF_X1);
    float* x2 = (float*)(ws + OFF_X2);
    unsigned* cnt  = (unsigned*)(ws + OFF_CNT);
    unsigned* hist = (unsigned*)(ws + OFF_HIST);
    float* desc    = (float*)(ws + OFF_DESC);

    int W = out_size / (B_ * (TOPK + ENDK));  // 1 + neg_min

    hipMemsetAsync(hist, 0, (size_t)64 * NBINS * 4, stream);
    hipMemsetAsync(cnt, 0, 64, stream);

    k_dense<<<H_, 64, 0, stream>>>(q, dw, db, x1, 1);
    k_dense<<<H_, 64, 0, stream>>>(x1, ow, ob, x2, 0);
    k_norm<<<B_, 64, 0, stream>>>(x2, lq);
    k_cos_hist<<<K_ / 256, 512, 0, stream>>>(lq, fq, labels, lblq, hist);
    k_count1<<<64, 256, 0, stream>>>(lblq, cnt);
    k_posmin<<<1, 64, 0, stream>>>(labels, cnt, cnt + 1);
    k_expand<<<64, 1024, 0, stream>>>(hist, desc);
    k_write<<<B_ * (TOPK + ENDK), 512, 0, stream>>>(desc, cnt + 1, (float*)d_out, W);
}

// Round 2
// 394.241 us; speedup vs baseline: 2.1372x; 2.1372x over previous
//
#include <hip/hip_runtime.h>
#include <hip/hip_bf16.h>

#define B_ 32
#define H_ 768
#define K_ 65536
#define TOPK 25
#define ENDK 25
#define NBINS 65536
#define DSTR 36864   // floats per (b,g) desc segment

// ws byte offsets
#define OFF_LQ   0
#define OFF_X1   98304
#define OFF_X2   196608
#define OFF_CNT  294912      // u32[16]: [0]=count1, [1]=pos_min
#define OFF_HIST 524288      // u32[64*65536] = 16 MB
#define OFF_DESC 17825792    // float[64*DSTR] = 9.4 MB

// x_out[b][j] = (tanh?) ( sum_e in[b][e]*w[j][e] + bias[j] ); 4 waves/block, wave per j
__global__ __launch_bounds__(256) void k_dense(const float* __restrict__ in, const float* __restrict__ w,
                        const float* __restrict__ bias, float* __restrict__ out,
                        int apply_tanh) {
    int j = blockIdx.x * 4 + (threadIdx.x >> 6);
    int lane = threadIdx.x & 63;
    float acc[B_];
#pragma unroll
    for (int b = 0; b < B_; ++b) acc[b] = 0.f;
#pragma unroll
    for (int c = 0; c < 12; ++c) {
        float wv = w[j * H_ + lane + 64 * c];
#pragma unroll
        for (int b = 0; b < B_; ++b) acc[b] += in[b * H_ + lane + 64 * c] * wv;
    }
    float bj = bias[j];
#pragma unroll
    for (int b = 0; b < B_; ++b) {
        float v = acc[b];
#pragma unroll
        for (int off = 32; off > 0; off >>= 1) v += __shfl_xor(v, off, 64);
        if (lane == b) {
            float r = v + bj;
            out[b * H_ + j] = apply_tanh ? tanhf(r) : r;
        }
    }
}

__global__ void k_norm(const float* __restrict__ x2, float* __restrict__ lq) {
    int b = blockIdx.x, lane = threadIdx.x;
    float v[12];
    float ss = 0.f;
#pragma unroll
    for (int c = 0; c < 12; ++c) {
        v[c] = x2[b * H_ + lane + 64 * c];
        ss += v[c] * v[c];
    }
#pragma unroll
    for (int off = 32; off > 0; off >>= 1) ss += __shfl_xor(ss, off, 64);
    float rn = 1.0f / sqrtf(ss);
#pragma unroll
    for (int c = 0; c < 12; ++c) lq[b * H_ + lane + 64 * c] = v[c] * rn;
}

// Register-blocked GEMM (32 x 65536 x 768) + histogram binning.
// Block: 256 threads, tile 128k x 32b. Thread: 4b x 4k lane-local accumulators.
// fq staged in LDS with XOR swizzle; lq chunk staged in LDS (broadcast reads).
__global__ __launch_bounds__(256) void k_gemm_hist(
    const float* __restrict__ lq, const float* __restrict__ fq,
    const int* __restrict__ labels, const int* __restrict__ lblq,
    unsigned* __restrict__ hist) {
    __shared__ float fq_lds[128][32];
    __shared__ float lq_lds[32][32];
    const int t = threadIdx.x;
    const int kbase = blockIdx.x * 128;
    const int kq = t & 31;          // k-quad id (0..31)
    const int b0 = (t >> 5) * 4;    // 0,4,...,28
    const int k0 = kq * 4;
    const int swz = kq & 7;
    const int sk = t >> 3;          // staging row helper (0..31)
    const int sh = t & 7;           // staging float4 col (0..7)

    float acc[4][4];
#pragma unroll
    for (int j = 0; j < 4; ++j)
#pragma unroll
        for (int i = 0; i < 4; ++i) acc[j][i] = 0.f;

    // prefetch chunk 0 into registers
    float4 pf[4]; float4 pl;
#pragma unroll
    for (int p = 0; p < 4; ++p)
        pf[p] = *(const float4*)(fq + (size_t)(kbase + p * 32 + sk) * H_ + sh * 4);
    pl = *(const float4*)(lq + sk * H_ + sh * 4);

    for (int ch = 0; ch < 24; ++ch) {
        __syncthreads();   // previous chunk's compute done; LDS reusable
#pragma unroll
        for (int p = 0; p < 4; ++p) {
            int kk = p * 32 + sk;
            int cp = sh ^ ((kk >> 2) & 7);
            *(float4*)&fq_lds[kk][cp * 4] = pf[p];
        }
        *(float4*)&lq_lds[sk][sh * 4] = pl;
        if (ch + 1 < 24) {     // issue next chunk's global loads; fly under compute
            int hb = (ch + 1) * 32;
#pragma unroll
            for (int p = 0; p < 4; ++p)
                pf[p] = *(const float4*)(fq + (size_t)(kbase + p * 32 + sk) * H_ + hb + sh * 4);
            pl = *(const float4*)(lq + sk * H_ + hb + sh * 4);
        }
        __syncthreads();   // LDS tile ready
#pragma unroll
        for (int hh = 0; hh < 8; ++hh) {
            int cp = (hh ^ swz) * 4;
            float4 fv0 = *(const float4*)&fq_lds[k0 + 0][cp];
            float4 fv1 = *(const float4*)&fq_lds[k0 + 1][cp];
            float4 fv2 = *(const float4*)&fq_lds[k0 + 2][cp];
            float4 fv3 = *(const float4*)&fq_lds[k0 + 3][cp];
            float4 lv0 = *(const float4*)&lq_lds[b0 + 0][hh * 4];
            float4 lv1 = *(const float4*)&lq_lds[b0 + 1][hh * 4];
            float4 lv2 = *(const float4*)&lq_lds[b0 + 2][hh * 4];
            float4 lv3 = *(const float4*)&lq_lds[b0 + 3][hh * 4];
#define DOT(aj, lv) \
            acc[aj][0] += lv.x * fv0.x + lv.y * fv0.y + lv.z * fv0.z + lv.w * fv0.w; \
            acc[aj][1] += lv.x * fv1.x + lv.y * fv1.y + lv.z * fv1.z + lv.w * fv1.w; \
            acc[aj][2] += lv.x * fv2.x + lv.y * fv2.y + lv.z * fv2.z + lv.w * fv2.w; \
            acc[aj][3] += lv.x * fv3.x + lv.y * fv3.y + lv.z * fv3.z + lv.w * fv3.w;
            DOT(0, lv0) DOT(1, lv1) DOT(2, lv2) DOT(3, lv3)
#undef DOT
        }
    }

    int labs[4];
#pragma unroll
    for (int j = 0; j < 4; ++j) labs[j] = labels[b0 + j];
#pragma unroll
    for (int i = 0; i < 4; ++i) {
        int gk = kbase + k0 + i;
        int lb = lblq[gk];
#pragma unroll
        for (int j = 0; j < 4; ++j) {
            int g = (labs[j] == lb) ? 1 : 0;
            float v = acc[j][i];
            int bin = (int)floorf((v + 0.5f) * 65536.0f);
            bin = bin < 0 ? 0 : (bin > 65535 ? 65535 : bin);
            atomicAdd(&hist[(unsigned)((((b0 + j) << 1) | g) << 16) + (unsigned)bin], 1u);
        }
    }
}

__global__ void k_count1(const int* __restrict__ lblq, unsigned* __restrict__ cnt) {
    int idx = blockIdx.x * blockDim.x + threadIdx.x;  // 16384 threads
    unsigned local = 0;
    for (int k = idx; k < K_; k += 16384) local += (unsigned)lblq[k];
#pragma unroll
    for (int off = 32; off > 0; off >>= 1) local += (unsigned)__shfl_xor((int)local, off, 64);
    if ((threadIdx.x & 63) == 0) atomicAdd(cnt, local);
}

__global__ void k_posmin(const int* __restrict__ labels, const unsigned* __restrict__ cnt,
                         unsigned* __restrict__ posmin) {
    int lane = threadIdx.x;
    unsigned c1 = *cnt;
    unsigned cp = 0x7fffffffu;
    if (lane < B_) cp = (labels[lane] == 1) ? c1 : ((unsigned)K_ - c1);
#pragma unroll
    for (int off = 32; off > 0; off >>= 1) {
        unsigned o = (unsigned)__shfl_xor((int)cp, off, 64);
        cp = o < cp ? o : cp;
    }
    if (lane == 0) *posmin = cp;
}

// Expand histogram (descending) into sorted value array. 4 blocks per segment.
__global__ __launch_bounds__(1024) void k_expand(const unsigned* __restrict__ hist,
                                                 float* __restrict__ desc) {
    int seg = blockIdx.x >> 2, q = blockIdx.x & 3;
    int t = threadIdx.x, lane = t & 63, wid = t >> 6;   // 16 waves
    const unsigned* h = hist + (size_t)seg * NBINS + t * 64;
    unsigned s = 0;
    for (int i = 0; i < 64; ++i) s += h[i];
    // inclusive scan over 1024 threads: wave shfl-scan + 16-wave combine
    unsigned v = s;
#pragma unroll
    for (int off = 1; off < 64; off <<= 1) {
        unsigned u = (unsigned)__shfl_up((int)v, off, 64);
        if (lane >= off) v += u;
    }
    __shared__ unsigned wsum[16];
    if (lane == 63) wsum[wid] = v;
    __syncthreads();
    unsigned wexcl = 0, tot = 0;
#pragma unroll
    for (int i2 = 0; i2 < 16; ++i2) {
        unsigned x = wsum[i2];
        if (i2 < wid) wexcl += x;
        tot += x;
    }
    unsigned incl = wexcl + v;
    if ((t >> 8) == q) {
        unsigned run = tot - incl;   // elements in bins above my group
        float* out = desc + (size_t)seg * DSTR;
        for (int i = 63; i >= 0; --i) {
            unsigned c = h[i];
            float val = ((float)(t * 64 + i) + 0.5f) * (1.0f / 65536.0f) - 0.5f;
            unsigned end = run + c;
            if (end > (unsigned)DSTR) end = (unsigned)DSTR;
            for (unsigned p = run; p < end; ++p) out[p] = val;
            run += c;
        }
    }
}

// Broadcast writer: read each neg value once, write to 50 repeat rows (coalesced).
__global__ __launch_bounds__(1024) void k_bcast(const float* __restrict__ desc,
                                                const unsigned* __restrict__ posmin,
                                                float* __restrict__ out, int W) {
    int b = blockIdx.x;       // 0..31
    int cb = blockIdx.y;
    const float invT = 14.285714285714286f;  // 1/0.07
    if (cb == 0 && threadIdx.x < (TOPK + ENDK)) {
        int pm = (int)*posmin;
        const float* pos = desc + (size_t)(b * 2 + 1) * DSTR;
        int j = threadIdx.x;
        float pv = (j < TOPK) ? pos[j] : pos[pm - ENDK + (j - TOPK)];
        out[(size_t)(b * (TOPK + ENDK) + j) * W] = pv * invT;
    }
    int c = 1 + cb * 1024 + threadIdx.x;
    if (c < W) {
        const float* neg = desc + (size_t)(b * 2) * DSTR;
        float v = neg[c - 1] * invT;
        float* o = out + (size_t)b * (TOPK + ENDK) * W + c;
#pragma unroll
        for (int r = 0; r < TOPK + ENDK; ++r) o[(size_t)r * W] = v;
    }
}

extern "C" void kernel_launch(void* const* d_in, const int* in_sizes, int n_in,
                              void* d_out, int out_size, void* d_ws, size_t ws_size,
                              hipStream_t stream) {
    const float* q   = (const float*)d_in[0];
    const float* dw  = (const float*)d_in[1];
    const float* db  = (const float*)d_in[2];
    const float* ow  = (const float*)d_in[3];
    const float* ob  = (const float*)d_in[4];
    const int* labels = (const int*)d_in[5];
    const int* lblq   = (const int*)d_in[6];
    const float* fq   = (const float*)d_in[7];

    char* ws = (char*)d_ws;
    float* lq = (float*)(ws + OFF_LQ);
    float* x1 = (float*)(ws + OFF_X1);
    float* x2 = (float*)(ws + OFF_X2);
    unsigned* cnt  = (unsigned*)(ws + OFF_CNT);
    unsigned* hist = (unsigned*)(ws + OFF_HIST);
    float* desc    = (float*)(ws + OFF_DESC);

    int W = out_size / (B_ * (TOPK + ENDK));  // 1 + neg_min

    hipMemsetAsync(hist, 0, (size_t)64 * NBINS * 4, stream);
    hipMemsetAsync(cnt, 0, 64, stream);

    k_dense<<<H_ / 4, 256, 0, stream>>>(q, dw, db, x1, 1);
    k_dense<<<H_ / 4, 256, 0, stream>>>(x1, ow, ob, x2, 0);
    k_norm<<<B_, 64, 0, stream>>>(x2, lq);
    k_gemm_hist<<<K_ / 128, 256, 0, stream>>>(lq, fq, labels, lblq, hist);
    k_count1<<<64, 256, 0, stream>>>(lblq, cnt);
    k_posmin<<<1, 64, 0, stream>>>(labels, cnt, cnt + 1);
    k_expand<<<256, 1024, 0, stream>>>(hist, desc);

    dim3 gb(B_, (unsigned)((W - 1 + 1023) / 1024));
    k_bcast<<<gb, 1024, 0, stream>>>(desc, cnt + 1, (float*)d_out, W);
}

// Round 3
// 284.495 us; speedup vs baseline: 2.9616x; 1.3858x over previous
//
#include <hip/hip_runtime.h>
#include <hip/hip_bf16.h>

#define B_ 32
#define H_ 768
#define K_ 65536
#define TOPK 25
#define ENDK 25
#define NBINS 65536
#define DSTR 36864   // floats per (b,g) desc segment

// ws byte offsets
#define OFF_LQT  0           // bf16 tiled lq: 24 chunks * 32 rows * 32 k * 2B = 48 KB
#define OFF_X1   98304
#define OFF_X2   196608
#define OFF_CNT  294912      // u32[16]: [0]=count1, [1]=pos_min
#define OFF_HIST 524288      // u32[64*65536] = 16 MB
#define OFF_DESC 17825792    // float[64*DSTR] = 9.4 MB

typedef __attribute__((ext_vector_type(8))) short short8v;
typedef __attribute__((ext_vector_type(4))) float f32x4;

__device__ inline short f2bf(float f) {
    unsigned u = __builtin_bit_cast(unsigned, f);
    unsigned r = (u + 0x7FFFu + ((u >> 16) & 1u)) >> 16;   // RNE
    return (short)r;
}

// x_out[b][j] = (tanh?) ( sum_e in[b][e]*w[j][e] + bias[j] ); 4 waves/block, wave per j
__global__ __launch_bounds__(256) void k_dense(const float* __restrict__ in, const float* __restrict__ w,
                        const float* __restrict__ bias, float* __restrict__ out,
                        int apply_tanh) {
    int j = blockIdx.x * 4 + (threadIdx.x >> 6);
    int lane = threadIdx.x & 63;
    float acc[B_];
#pragma unroll
    for (int b = 0; b < B_; ++b) acc[b] = 0.f;
#pragma unroll
    for (int c = 0; c < 12; ++c) {
        float wv = w[j * H_ + lane + 64 * c];
#pragma unroll
        for (int b = 0; b < B_; ++b) acc[b] += in[b * H_ + lane + 64 * c] * wv;
    }
    float bj = bias[j];
#pragma unroll
    for (int b = 0; b < B_; ++b) {
        float v = acc[b];
#pragma unroll
        for (int off = 32; off > 0; off >>= 1) v += __shfl_xor(v, off, 64);
        if (lane == b) {
            float r = v + bj;
            out[b * H_ + j] = apply_tanh ? tanhf(r) : r;
        }
    }
}

// Normalize rows of x2 and emit bf16 A-fragments tiled as lqt[ch][row][kk]:
// element (b, k) -> lqt[(k>>5)*1024 + b*32 + (k&31)]
__global__ void k_norm(const float* __restrict__ x2, short* __restrict__ lqt) {
    int b = blockIdx.x, lane = threadIdx.x;
    float v[12];
    float ss = 0.f;
#pragma unroll
    for (int c = 0; c < 12; ++c) {
        v[c] = x2[b * H_ + lane + 64 * c];
        ss += v[c] * v[c];
    }
#pragma unroll
    for (int off = 32; off > 0; off >>= 1) ss += __shfl_xor(ss, off, 64);
    float rn = 1.0f / sqrtf(ss);
#pragma unroll
    for (int c = 0; c < 12; ++c) {
        int k = lane + 64 * c;
        lqt[(k >> 5) * 1024 + b * 32 + (k & 31)] = f2bf(v[c] * rn);
    }
}

// MFMA GEMM (32 x 65536 x 768, bf16 in / fp32 acc) + histogram binning.
// No LDS, no barriers. Wave owns a 16-row fq tile; 2 M-tiles of 16.
__global__ __launch_bounds__(256) void k_gemm_hist(
    const float* __restrict__ fq, const short* __restrict__ lqt,
    const int* __restrict__ labels, const int* __restrict__ lblq,
    unsigned* __restrict__ hist) {
    const int l = threadIdx.x & 63;
    const int w = threadIdx.x >> 6;
    const int gw = blockIdx.x * 4 + w;        // 0..4095
    const int nb = gw * 16;
    const int r = l & 15, o = l >> 4;

    const float* fbase = fq + (size_t)(nb + r) * H_ + o * 8;
    const short* abase = lqt + r * 32 + o * 8;

    f32x4 acc0 = {0.f, 0.f, 0.f, 0.f};
    f32x4 acc1 = {0.f, 0.f, 0.f, 0.f};
    const int myql = lblq[nb + r];

#pragma unroll 4
    for (int ch = 0; ch < 24; ++ch) {
        float4 b0 = *(const float4*)(fbase + ch * 32);
        float4 b1 = *(const float4*)(fbase + ch * 32 + 4);
        short8v bf;
        bf[0] = f2bf(b0.x); bf[1] = f2bf(b0.y); bf[2] = f2bf(b0.z); bf[3] = f2bf(b0.w);
        bf[4] = f2bf(b1.x); bf[5] = f2bf(b1.y); bf[6] = f2bf(b1.z); bf[7] = f2bf(b1.w);
        short8v a0 = *(const short8v*)(abase + ch * 1024);
        short8v a1 = *(const short8v*)(abase + ch * 1024 + 512);
        acc0 = __builtin_amdgcn_mfma_f32_16x16x32_bf16(a0, bf, acc0, 0, 0, 0);
        acc1 = __builtin_amdgcn_mfma_f32_16x16x32_bf16(a1, bf, acc1, 0, 0, 0);
    }

    // D layout: col = lane&15 (n), row = (lane>>4)*4 + reg (m)  [m89]
#define EMIT(ACC, MT) \
    _Pragma("unroll") \
    for (int i = 0; i < 4; ++i) { \
        int m = (MT) * 16 + o * 4 + i; \
        int g = (labels[m] == myql) ? 1 : 0; \
        float v = ACC[i]; \
        int bin = (int)floorf((v + 0.5f) * 65536.0f); \
        bin = bin < 0 ? 0 : (bin > 65535 ? 65535 : bin); \
        atomicAdd(&hist[(unsigned)(((m << 1) | g) << 16) + (unsigned)bin], 1u); \
    }
    EMIT(acc0, 0)
    EMIT(acc1, 1)
#undef EMIT
}

__global__ void k_count1(const int* __restrict__ lblq, unsigned* __restrict__ cnt) {
    int idx = blockIdx.x * blockDim.x + threadIdx.x;  // 16384 threads
    unsigned local = 0;
    for (int k = idx; k < K_; k += 16384) local += (unsigned)lblq[k];
#pragma unroll
    for (int off = 32; off > 0; off >>= 1) local += (unsigned)__shfl_xor((int)local, off, 64);
    if ((threadIdx.x & 63) == 0) atomicAdd(cnt, local);
}

__global__ void k_posmin(const int* __restrict__ labels, const unsigned* __restrict__ cnt,
                         unsigned* __restrict__ posmin) {
    int lane = threadIdx.x;
    unsigned c1 = *cnt;
    unsigned cp = 0x7fffffffu;
    if (lane < B_) cp = (labels[lane] == 1) ? c1 : ((unsigned)K_ - c1);
#pragma unroll
    for (int off = 32; off > 0; off >>= 1) {
        unsigned o = (unsigned)__shfl_xor((int)cp, off, 64);
        cp = o < cp ? o : cp;
    }
    if (lane == 0) *posmin = cp;
}

// Expand histogram (descending) into sorted value array. 4 blocks per segment.
__global__ __launch_bounds__(1024) void k_expand(const unsigned* __restrict__ hist,
                                                 float* __restrict__ desc) {
    int seg = blockIdx.x >> 2, q = blockIdx.x & 3;
    int t = threadIdx.x, lane = t & 63, wid = t >> 6;   // 16 waves
    const unsigned* h = hist + (size_t)seg * NBINS + t * 64;
    unsigned s = 0;
    for (int i = 0; i < 64; ++i) s += h[i];
    unsigned v = s;
#pragma unroll
    for (int off = 1; off < 64; off <<= 1) {
        unsigned u = (unsigned)__shfl_up((int)v, off, 64);
        if (lane >= off) v += u;
    }
    __shared__ unsigned wsum[16];
    if (lane == 63) wsum[wid] = v;
    __syncthreads();
    unsigned wexcl = 0, tot = 0;
#pragma unroll
    for (int i2 = 0; i2 < 16; ++i2) {
        unsigned x = wsum[i2];
        if (i2 < wid) wexcl += x;
        tot += x;
    }
    unsigned incl = wexcl + v;
    if ((t >> 8) == q) {
        unsigned run = tot - incl;   // elements in bins above mine
        float* out = desc + (size_t)seg * DSTR;
        for (int i = 63; i >= 0; --i) {
            unsigned c = h[i];
            float val = ((float)(t * 64 + i) + 0.5f) * (1.0f / 65536.0f) - 0.5f;
            unsigned end = run + c;
            if (end > (unsigned)DSTR) end = (unsigned)DSTR;
            for (unsigned p = run; p < end; ++p) out[p] = val;
            run += c;
        }
    }
}

// Broadcast writer: read each neg value once, write to 50 repeat rows (coalesced).
__global__ __launch_bounds__(1024) void k_bcast(const float* __restrict__ desc,
                                                const unsigned* __restrict__ posmin,
                                                float* __restrict__ out, int W) {
    int b = blockIdx.x;       // 0..31
    int cb = blockIdx.y;
    const float invT = 14.285714285714286f;  // 1/0.07
    if (cb == 0 && threadIdx.x < (TOPK + ENDK)) {
        int pm = (int)*posmin;
        const float* pos = desc + (size_t)(b * 2 + 1) * DSTR;
        int j = threadIdx.x;
        float pv = (j < TOPK) ? pos[j] : pos[pm - ENDK + (j - TOPK)];
        out[(size_t)(b * (TOPK + ENDK) + j) * W] = pv * invT;
    }
    int c = 1 + cb * 1024 + threadIdx.x;
    if (c < W) {
        const float* neg = desc + (size_t)(b * 2) * DSTR;
        float v = neg[c - 1] * invT;
        float* o = out + (size_t)b * (TOPK + ENDK) * W + c;
#pragma unroll
        for (int r = 0; r < TOPK + ENDK; ++r) o[(size_t)r * W] = v;
    }
}

extern "C" void kernel_launch(void* const* d_in, const int* in_sizes, int n_in,
                              void* d_out, int out_size, void* d_ws, size_t ws_size,
                              hipStream_t stream) {
    const float* q   = (const float*)d_in[0];
    const float* dw  = (const float*)d_in[1];
    const float* db  = (const float*)d_in[2];
    const float* ow  = (const float*)d_in[3];
    const float* ob  = (const float*)d_in[4];
    const int* labels = (const int*)d_in[5];
    const int* lblq   = (const int*)d_in[6];
    const float* fq   = (const float*)d_in[7];

    char* ws = (char*)d_ws;
    short* lqt = (short*)(ws + OFF_LQT);
    float* x1 = (float*)(ws + OFF_X1);
    float* x2 = (float*)(ws + OFF_X2);
    unsigned* cnt  = (unsigned*)(ws + OFF_CNT);
    unsigned* hist = (unsigned*)(ws + OFF_HIST);
    float* desc    = (float*)(ws + OFF_DESC);

    int W = out_size / (B_ * (TOPK + ENDK));  // 1 + neg_min

    hipMemsetAsync(hist, 0, (size_t)64 * NBINS * 4, stream);
    hipMemsetAsync(cnt, 0, 64, stream);

    k_dense<<<H_ / 4, 256, 0, stream>>>(q, dw, db, x1, 1);
    k_dense<<<H_ / 4, 256, 0, stream>>>(x1, ow, ob, x2, 0);
    k_norm<<<B_, 64, 0, stream>>>(x2, lqt);
    k_gemm_hist<<<K_ / 64, 256, 0, stream>>>(fq, lqt, labels, lblq, hist);
    k_count1<<<64, 256, 0, stream>>>(lblq, cnt);
    k_posmin<<<1, 64, 0, stream>>>(labels, cnt, cnt + 1);
    k_expand<<<256, 1024, 0, stream>>>(hist, desc);

    dim3 gb(B_, (unsigned)((W - 1 + 1023) / 1024));
    k_bcast<<<gb, 1024, 0, stream>>>(desc, cnt + 1, (float*)d_out, W);
}

// Round 4
// 225.355 us; speedup vs baseline: 3.7389x; 1.2624x over previous
//
#include <hip/hip_runtime.h>
#include <hip/hip_bf16.h>

#define B_ 32
#define H_ 768
#define K_ 65536
#define TOPK 25
#define ENDK 25
#define NBINS 65536

// ws byte offsets
#define OFF_LQT  0           // bf16 tiled lq: 24 chunks * 32 rows * 32 k * 2B = 48 KB
#define OFF_X1   98304
#define OFF_X2   196608
#define OFF_CNT  294912      // u32[16]: [0]=count1, [1]=pos_min
#define OFF_HIST 524288      // u32[64*65536] = 16 MB  (becomes suffix-CDF in-place)

typedef __attribute__((ext_vector_type(8))) short short8v;
typedef __attribute__((ext_vector_type(4))) float f32x4;

__device__ inline short f2bf(float f) {
    unsigned u = __builtin_bit_cast(unsigned, f);
    unsigned r = (u + 0x7FFFu + ((u >> 16) & 1u)) >> 16;   // RNE
    return (short)r;
}

// x_out[b][j] = (tanh?) ( sum_e in[b][e]*w[j][e] + bias[j] ); 4 waves/block, wave per j
__global__ __launch_bounds__(256) void k_dense(const float* __restrict__ in, const float* __restrict__ w,
                        const float* __restrict__ bias, float* __restrict__ out,
                        int apply_tanh) {
    int j = blockIdx.x * 4 + (threadIdx.x >> 6);
    int lane = threadIdx.x & 63;
    float acc[B_];
#pragma unroll
    for (int b = 0; b < B_; ++b) acc[b] = 0.f;
#pragma unroll
    for (int c = 0; c < 12; ++c) {
        float wv = w[j * H_ + lane + 64 * c];
#pragma unroll
        for (int b = 0; b < B_; ++b) acc[b] += in[b * H_ + lane + 64 * c] * wv;
    }
    float bj = bias[j];
#pragma unroll
    for (int b = 0; b < B_; ++b) {
        float v = acc[b];
#pragma unroll
        for (int off = 32; off > 0; off >>= 1) v += __shfl_xor(v, off, 64);
        if (lane == b) {
            float r = v + bj;
            out[b * H_ + j] = apply_tanh ? tanhf(r) : r;
        }
    }
}

// Normalize rows of x2 and emit bf16 A-fragments tiled as lqt[ch][row][kk]:
// element (b, k) -> lqt[(k>>5)*1024 + b*32 + (k&31)]
__global__ void k_norm(const float* __restrict__ x2, short* __restrict__ lqt) {
    int b = blockIdx.x, lane = threadIdx.x;
    float v[12];
    float ss = 0.f;
#pragma unroll
    for (int c = 0; c < 12; ++c) {
        v[c] = x2[b * H_ + lane + 64 * c];
        ss += v[c] * v[c];
    }
#pragma unroll
    for (int off = 32; off > 0; off >>= 1) ss += __shfl_xor(ss, off, 64);
    float rn = 1.0f / sqrtf(ss);
#pragma unroll
    for (int c = 0; c < 12; ++c) {
        int k = lane + 64 * c;
        lqt[(k >> 5) * 1024 + b * 32 + (k & 31)] = f2bf(v[c] * rn);
    }
}

// MFMA GEMM (32 x 65536 x 768, bf16 in / fp32 acc) + histogram binning.
// H-reduction split across wave pairs (12 chunks each); combine via LDS.
// 2048 blocks x 4 waves = 8192 waves = 32 waves/CU.
__global__ __launch_bounds__(256) void k_gemm_hist(
    const float* __restrict__ fq, const short* __restrict__ lqt,
    const int* __restrict__ labels, const int* __restrict__ lblq,
    unsigned* __restrict__ hist) {
    __shared__ float xch[2][64][8];
    const int l = threadIdx.x & 63;
    const int w = threadIdx.x >> 6;       // 0..3
    const int pair = w >> 1;              // 0..1 : which 16-row fq tile
    const int half = w & 1;               // 0..1 : which H half
    const int nb = (blockIdx.x * 2 + pair) * 16;
    const int r = l & 15, o = l >> 4;

    const float* fbase = fq + (size_t)(nb + r) * H_ + half * 384 + o * 8;
    const short* abase = lqt + half * 12 * 1024 + r * 32 + o * 8;

    f32x4 acc0 = {0.f, 0.f, 0.f, 0.f};
    f32x4 acc1 = {0.f, 0.f, 0.f, 0.f};

#pragma unroll 4
    for (int ch = 0; ch < 12; ++ch) {
        float4 b0 = *(const float4*)(fbase + ch * 32);
        float4 b1 = *(const float4*)(fbase + ch * 32 + 4);
        short8v bf;
        bf[0] = f2bf(b0.x); bf[1] = f2bf(b0.y); bf[2] = f2bf(b0.z); bf[3] = f2bf(b0.w);
        bf[4] = f2bf(b1.x); bf[5] = f2bf(b1.y); bf[6] = f2bf(b1.z); bf[7] = f2bf(b1.w);
        short8v a0 = *(const short8v*)(abase + ch * 1024);
        short8v a1 = *(const short8v*)(abase + ch * 1024 + 512);
        acc0 = __builtin_amdgcn_mfma_f32_16x16x32_bf16(a0, bf, acc0, 0, 0, 0);
        acc1 = __builtin_amdgcn_mfma_f32_16x16x32_bf16(a1, bf, acc1, 0, 0, 0);
    }

    if (half == 1) {
#pragma unroll
        for (int i = 0; i < 4; ++i) {
            xch[pair][l][i] = acc0[i];
            xch[pair][l][i + 4] = acc1[i];
        }
    }
    __syncthreads();
    if (half == 0) {
        const int myql = lblq[nb + r];
#pragma unroll
        for (int i = 0; i < 4; ++i) {
            acc0[i] += xch[pair][l][i];
            acc1[i] += xch[pair][l][i + 4];
        }
        // D layout: col = lane&15 (fq row), row m = (lane>>4)*4 + reg (b index)
#define EMIT(ACC, MT) \
        _Pragma("unroll") \
        for (int i = 0; i < 4; ++i) { \
            int m = (MT) * 16 + o * 4 + i; \
            int g = (labels[m] == myql) ? 1 : 0; \
            float v = ACC[i]; \
            int bin = (int)floorf((v + 0.5f) * 65536.0f); \
            bin = bin < 0 ? 0 : (bin > 65535 ? 65535 : bin); \
            atomicAdd(&hist[(unsigned)(((m << 1) | g) << 16) + (unsigned)bin], 1u); \
        }
        EMIT(acc0, 0)
        EMIT(acc1, 1)
#undef EMIT
    }
}

__global__ void k_count1(const int* __restrict__ lblq, unsigned* __restrict__ cnt) {
    int idx = blockIdx.x * blockDim.x + threadIdx.x;  // 16384 threads
    unsigned local = 0;
    for (int k = idx; k < K_; k += 16384) local += (unsigned)lblq[k];
#pragma unroll
    for (int off = 32; off > 0; off >>= 1) local += (unsigned)__shfl_xor((int)local, off, 64);
    if ((threadIdx.x & 63) == 0) atomicAdd(cnt, local);
}

__global__ void k_posmin(const int* __restrict__ labels, const unsigned* __restrict__ cnt,
                         unsigned* __restrict__ posmin) {
    int lane = threadIdx.x;
    unsigned c1 = *cnt;
    unsigned cp = 0x7fffffffu;
    if (lane < B_) cp = (labels[lane] == 1) ? c1 : ((unsigned)K_ - c1);
#pragma unroll
    for (int off = 32; off > 0; off >>= 1) {
        unsigned o = (unsigned)__shfl_xor((int)cp, off, 64);
        cp = o < cp ? o : cp;
    }
    if (lane == 0) *posmin = cp;
}

// Convert hist in-place to suffix-CDF: S[i] = # elements in bins >= i.
// One block per segment; thread t owns bins [t*64, t*64+64).
__global__ __launch_bounds__(1024) void k_scan(unsigned* __restrict__ hist) {
    int seg = blockIdx.x;
    unsigned* h = hist + (size_t)seg * NBINS + threadIdx.x * 64;
    int lane = threadIdx.x & 63, wid = threadIdx.x >> 6;
    unsigned s = 0;
    for (int i = 0; i < 64; ++i) s += h[i];
    unsigned v = s;
#pragma unroll
    for (int off = 1; off < 64; off <<= 1) {
        unsigned u = (unsigned)__shfl_up((int)v, off, 64);
        if (lane >= off) v += u;
    }
    __shared__ unsigned wsum[16];
    if (lane == 63) wsum[wid] = v;
    __syncthreads();
    unsigned wexcl = 0, tot = 0;
#pragma unroll
    for (int i = 0; i < 16; ++i) {
        unsigned x = wsum[i];
        if (i < wid) wexcl += x;
        tot += x;
    }
    unsigned run = wexcl + v - s;   // elements in bins below mine (ascending prefix)
    for (int i = 0; i < 64; ++i) {
        unsigned c = h[i];
        h[i] = tot - run;           // S[i]
        run += c;
    }
}

// rank p (descending) -> bin: largest i with S[i] > p  (then S[i] > p >= S[i+1])
__device__ inline int bsearch_bin(const unsigned* __restrict__ S, unsigned p) {
    int lo = 0, hi = NBINS;
#pragma unroll
    for (int it = 0; it < 17; ++it) {
        if (hi - lo > 1) {
            int mid = (lo + hi) >> 1;
            bool gt = S[mid] > p;
            lo = gt ? mid : lo;
            hi = gt ? hi : mid;
        }
    }
    return lo;
}

__device__ inline float bin_val(int bin) {
    return ((float)bin + 0.5f) * (1.0f / 65536.0f) - 0.5f;
}

// Output writer: rank-search the CDF, broadcast to 50 repeat rows (coalesced).
__global__ __launch_bounds__(1024) void k_out(const unsigned* __restrict__ S,
                                              const unsigned* __restrict__ posmin,
                                              float* __restrict__ out, int W) {
    int b = blockIdx.x;       // 0..31
    int cb = blockIdx.y;
    const float invT = 14.285714285714286f;  // 1/0.07
    if (cb == 0 && threadIdx.x < (TOPK + ENDK)) {
        int pm = (int)*posmin;
        int j = threadIdx.x;
        int p = (j < TOPK) ? j : (pm - ENDK + (j - TOPK));
        const unsigned* Sp = S + (size_t)(b * 2 + 1) * NBINS;
        int bin = bsearch_bin(Sp, (unsigned)p);
        out[(size_t)(b * (TOPK + ENDK) + j) * W] = bin_val(bin) * invT;
    }
    int c = 1 + cb * 1024 + threadIdx.x;
    if (c < W) {
        const unsigned* Sn = S + (size_t)(b * 2) * NBINS;
        int bin = bsearch_bin(Sn, (unsigned)(c - 1));
        float v = bin_val(bin) * invT;
        float* o = out + (size_t)b * (TOPK + ENDK) * W + c;
#pragma unroll
        for (int r = 0; r < TOPK + ENDK; ++r) o[(size_t)r * W] = v;
    }
}

extern "C" void kernel_launch(void* const* d_in, const int* in_sizes, int n_in,
                              void* d_out, int out_size, void* d_ws, size_t ws_size,
                              hipStream_t stream) {
    const float* q   = (const float*)d_in[0];
    const float* dw  = (const float*)d_in[1];
    const float* db  = (const float*)d_in[2];
    const float* ow  = (const float*)d_in[3];
    const float* ob  = (const float*)d_in[4];
    const int* labels = (const int*)d_in[5];
    const int* lblq   = (const int*)d_in[6];
    const float* fq   = (const float*)d_in[7];

    char* ws = (char*)d_ws;
    short* lqt = (short*)(ws + OFF_LQT);
    float* x1 = (float*)(ws + OFF_X1);
    float* x2 = (float*)(ws + OFF_X2);
    unsigned* cnt  = (unsigned*)(ws + OFF_CNT);
    unsigned* hist = (unsigned*)(ws + OFF_HIST);

    int W = out_size / (B_ * (TOPK + ENDK));  // 1 + neg_min

    hipMemsetAsync(hist, 0, (size_t)64 * NBINS * 4, stream);
    hipMemsetAsync(cnt, 0, 64, stream);

    k_dense<<<H_ / 4, 256, 0, stream>>>(q, dw, db, x1, 1);
    k_dense<<<H_ / 4, 256, 0, stream>>>(x1, ow, ob, x2, 0);
    k_norm<<<B_, 64, 0, stream>>>(x2, lqt);
    k_gemm_hist<<<K_ / 32, 256, 0, stream>>>(fq, lqt, labels, lblq, hist);
    k_count1<<<64, 256, 0, stream>>>(lblq, cnt);
    k_posmin<<<1, 64, 0, stream>>>(labels, cnt, cnt + 1);
    k_scan<<<64, 1024, 0, stream>>>(hist);

    dim3 gb(B_, (unsigned)((W - 1 + 1023) / 1024));
    k_out<<<gb, 1024, 0, stream>>>(hist, cnt + 1, (float*)d_out, W);
}

// Round 5
// 223.546 us; speedup vs baseline: 3.7691x; 1.0081x over previous
//
#include <hip/hip_runtime.h>
#include <hip/hip_bf16.h>

#define B_ 32
#define H_ 768
#define K_ 65536
#define TOPK 25
#define ENDK 25
#define NBINS 65536

// ws byte offsets
#define OFF_LQT  0           // bf16 tiled lq: 24 chunks * 32 rows * 32 k * 2B = 48 KB
#define OFF_X1   98304
#define OFF_X2   196608
#define OFF_CNT  294912      // u32[16]: [0]=count1, [1]=pos_min
#define OFF_HIST 524288      // u32[64*65536] = 16 MB  (becomes suffix-CDF in-place)

typedef __attribute__((ext_vector_type(8))) short short8v;
typedef __attribute__((ext_vector_type(4))) float f32x4;

__device__ inline short f2bf(float f) {
    unsigned u = __builtin_bit_cast(unsigned, f);
    unsigned r = (u + 0x7FFFu + ((u >> 16) & 1u)) >> 16;   // RNE
    return (short)r;
}

// Zero the 16 MB hist + cnt. Grid-stride float4: 2048 blocks x 256 thr.
__global__ __launch_bounds__(256) void k_zero(float4* __restrict__ hist4,
                                              unsigned* __restrict__ cnt) {
    const float4 z = {0.f, 0.f, 0.f, 0.f};
    int i = blockIdx.x * 256 + threadIdx.x;
    // 64*65536*4 B / 16 B = 1048576 float4s; 2048*256 = 524288 threads -> 2 each
    hist4[i] = z;
    hist4[i + 524288] = z;
    if (blockIdx.x == 0 && threadIdx.x < 16) cnt[threadIdx.x] = 0u;
}

// x_out[b][j] = (tanh?) ( sum_e in[b][e]*w[j][e] + bias[j] ); 4 waves/block, wave per j
__global__ __launch_bounds__(256) void k_dense(const float* __restrict__ in, const float* __restrict__ w,
                        const float* __restrict__ bias, float* __restrict__ out,
                        int apply_tanh) {
    int j = blockIdx.x * 4 + (threadIdx.x >> 6);
    int lane = threadIdx.x & 63;
    float acc[B_];
#pragma unroll
    for (int b = 0; b < B_; ++b) acc[b] = 0.f;
#pragma unroll
    for (int c = 0; c < 12; ++c) {
        float wv = w[j * H_ + lane + 64 * c];
#pragma unroll
        for (int b = 0; b < B_; ++b) acc[b] += in[b * H_ + lane + 64 * c] * wv;
    }
    float bj = bias[j];
#pragma unroll
    for (int b = 0; b < B_; ++b) {
        float v = acc[b];
#pragma unroll
        for (int off = 32; off > 0; off >>= 1) v += __shfl_xor(v, off, 64);
        if (lane == b) {
            float r = v + bj;
            out[b * H_ + j] = apply_tanh ? tanhf(r) : r;
        }
    }
}

// Normalize rows of x2 and emit bf16 A-fragments tiled as lqt[ch][row][kk]:
// element (b, k) -> lqt[(k>>5)*1024 + b*32 + (k&31)]
__global__ void k_norm(const float* __restrict__ x2, short* __restrict__ lqt) {
    int b = blockIdx.x, lane = threadIdx.x;
    float v[12];
    float ss = 0.f;
#pragma unroll
    for (int c = 0; c < 12; ++c) {
        v[c] = x2[b * H_ + lane + 64 * c];
        ss += v[c] * v[c];
    }
#pragma unroll
    for (int off = 32; off > 0; off >>= 1) ss += __shfl_xor(ss, off, 64);
    float rn = 1.0f / sqrtf(ss);
#pragma unroll
    for (int c = 0; c < 12; ++c) {
        int k = lane + 64 * c;
        lqt[(k >> 5) * 1024 + b * 32 + (k & 31)] = f2bf(v[c] * rn);
    }
}

// MFMA GEMM (32 x 65536 x 768, bf16 in / fp32 acc) + histogram binning.
// H-reduction split across wave pairs (12 chunks each); combine via LDS.
// 2048 blocks x 4 waves = 8192 waves = 32 waves/CU.
__global__ __launch_bounds__(256) void k_gemm_hist(
    const float* __restrict__ fq, const short* __restrict__ lqt,
    const int* __restrict__ labels, const int* __restrict__ lblq,
    unsigned* __restrict__ hist) {
    __shared__ float xch[2][64][8];
    const int l = threadIdx.x & 63;
    const int w = threadIdx.x >> 6;       // 0..3
    const int pair = w >> 1;              // 0..1 : which 16-row fq tile
    const int half = w & 1;               // 0..1 : which H half
    const int nb = (blockIdx.x * 2 + pair) * 16;
    const int r = l & 15, o = l >> 4;

    const float* fbase = fq + (size_t)(nb + r) * H_ + half * 384 + o * 8;
    const short* abase = lqt + half * 12 * 1024 + r * 32 + o * 8;

    f32x4 acc0 = {0.f, 0.f, 0.f, 0.f};
    f32x4 acc1 = {0.f, 0.f, 0.f, 0.f};

#pragma unroll 4
    for (int ch = 0; ch < 12; ++ch) {
        float4 b0 = *(const float4*)(fbase + ch * 32);
        float4 b1 = *(const float4*)(fbase + ch * 32 + 4);
        short8v bf;
        bf[0] = f2bf(b0.x); bf[1] = f2bf(b0.y); bf[2] = f2bf(b0.z); bf[3] = f2bf(b0.w);
        bf[4] = f2bf(b1.x); bf[5] = f2bf(b1.y); bf[6] = f2bf(b1.z); bf[7] = f2bf(b1.w);
        short8v a0 = *(const short8v*)(abase + ch * 1024);
        short8v a1 = *(const short8v*)(abase + ch * 1024 + 512);
        acc0 = __builtin_amdgcn_mfma_f32_16x16x32_bf16(a0, bf, acc0, 0, 0, 0);
        acc1 = __builtin_amdgcn_mfma_f32_16x16x32_bf16(a1, bf, acc1, 0, 0, 0);
    }

    if (half == 1) {
#pragma unroll
        for (int i = 0; i < 4; ++i) {
            xch[pair][l][i] = acc0[i];
            xch[pair][l][i + 4] = acc1[i];
        }
    }
    __syncthreads();
    if (half == 0) {
        const int myql = lblq[nb + r];
#pragma unroll
        for (int i = 0; i < 4; ++i) {
            acc0[i] += xch[pair][l][i];
            acc1[i] += xch[pair][l][i + 4];
        }
        // D layout: col = lane&15 (fq row), row m = (lane>>4)*4 + reg (b index)
#define EMIT(ACC, MT) \
        _Pragma("unroll") \
        for (int i = 0; i < 4; ++i) { \
            int m = (MT) * 16 + o * 4 + i; \
            int g = (labels[m] == myql) ? 1 : 0; \
            float v = ACC[i]; \
            int bin = (int)floorf((v + 0.5f) * 65536.0f); \
            bin = bin < 0 ? 0 : (bin > 65535 ? 65535 : bin); \
            atomicAdd(&hist[(unsigned)(((m << 1) | g) << 16) + (unsigned)bin], 1u); \
        }
        EMIT(acc0, 0)
        EMIT(acc1, 1)
#undef EMIT
    }
}

__global__ void k_count1(const int* __restrict__ lblq, unsigned* __restrict__ cnt) {
    int idx = blockIdx.x * blockDim.x + threadIdx.x;  // 16384 threads
    unsigned local = 0;
    for (int k = idx; k < K_; k += 16384) local += (unsigned)lblq[k];
#pragma unroll
    for (int off = 32; off > 0; off >>= 1) local += (unsigned)__shfl_xor((int)local, off, 64);
    if ((threadIdx.x & 63) == 0) atomicAdd(cnt, local);
}

__global__ void k_posmin(const int* __restrict__ labels, const unsigned* __restrict__ cnt,
                         unsigned* __restrict__ posmin) {
    int lane = threadIdx.x;
    unsigned c1 = *cnt;
    unsigned cp = 0x7fffffffu;
    if (lane < B_) cp = (labels[lane] == 1) ? c1 : ((unsigned)K_ - c1);
#pragma unroll
    for (int off = 32; off > 0; off >>= 1) {
        unsigned o = (unsigned)__shfl_xor((int)cp, off, 64);
        cp = o < cp ? o : cp;
    }
    if (lane == 0) *posmin = cp;
}

// Convert hist in-place to suffix-CDF: S[i] = # elements in bins >= i.
// One block per segment; thread t owns bins [t*64, t*64+64).
__global__ __launch_bounds__(1024) void k_scan(unsigned* __restrict__ hist) {
    int seg = blockIdx.x;
    unsigned* h = hist + (size_t)seg * NBINS + threadIdx.x * 64;
    int lane = threadIdx.x & 63, wid = threadIdx.x >> 6;
    unsigned s = 0;
    for (int i = 0; i < 64; ++i) s += h[i];
    unsigned v = s;
#pragma unroll
    for (int off = 1; off < 64; off <<= 1) {
        unsigned u = (unsigned)__shfl_up((int)v, off, 64);
        if (lane >= off) v += u;
    }
    __shared__ unsigned wsum[16];
    if (lane == 63) wsum[wid] = v;
    __syncthreads();
    unsigned wexcl = 0, tot = 0;
#pragma unroll
    for (int i = 0; i < 16; ++i) {
        unsigned x = wsum[i];
        if (i < wid) wexcl += x;
        tot += x;
    }
    unsigned run = wexcl + v - s;   // elements in bins below mine (ascending prefix)
    for (int i = 0; i < 64; ++i) {
        unsigned c = h[i];
        h[i] = tot - run;           // S[i]
        run += c;
    }
}

// rank p (descending) -> bin: largest i with S[i] > p  (then S[i] > p >= S[i+1])
__device__ inline int bsearch_bin(const unsigned* __restrict__ S, unsigned p) {
    int lo = 0, hi = NBINS;
#pragma unroll
    for (int it = 0; it < 17; ++it) {
        if (hi - lo > 1) {
            int mid = (lo + hi) >> 1;
            bool gt = S[mid] > p;
            lo = gt ? mid : lo;
            hi = gt ? hi : mid;
        }
    }
    return lo;
}

__device__ inline float bin_val(int bin) {
    return ((float)bin + 0.5f) * (1.0f / 65536.0f) - 0.5f;
}

// Output writer: rank-search the CDF, broadcast to 50 repeat rows (coalesced).
__global__ __launch_bounds__(1024) void k_out(const unsigned* __restrict__ S,
                                              const unsigned* __restrict__ posmin,
                                              float* __restrict__ out, int W) {
    int b = blockIdx.x;       // 0..31
    int cb = blockIdx.y;
    const float invT = 14.285714285714286f;  // 1/0.07
    if (cb == 0 && threadIdx.x < (TOPK + ENDK)) {
        int pm = (int)*posmin;
        int j = threadIdx.x;
        int p = (j < TOPK) ? j : (pm - ENDK + (j - TOPK));
        const unsigned* Sp = S + (size_t)(b * 2 + 1) * NBINS;
        int bin = bsearch_bin(Sp, (unsigned)p);
        out[(size_t)(b * (TOPK + ENDK) + j) * W] = bin_val(bin) * invT;
    }
    int c = 1 + cb * 1024 + threadIdx.x;
    if (c < W) {
        const unsigned* Sn = S + (size_t)(b * 2) * NBINS;
        int bin = bsearch_bin(Sn, (unsigned)(c - 1));
        float v = bin_val(bin) * invT;
        float* o = out + (size_t)b * (TOPK + ENDK) * W + c;
#pragma unroll
        for (int r = 0; r < TOPK + ENDK; ++r) o[(size_t)r * W] = v;
    }
}

extern "C" void kernel_launch(void* const* d_in, const int* in_sizes, int n_in,
                              void* d_out, int out_size, void* d_ws, size_t ws_size,
                              hipStream_t stream) {
    const float* q   = (const float*)d_in[0];
    const float* dw  = (const float*)d_in[1];
    const float* db  = (const float*)d_in[2];
    const float* ow  = (const float*)d_in[3];
    const float* ob  = (const float*)d_in[4];
    const int* labels = (const int*)d_in[5];
    const int* lblq   = (const int*)d_in[6];
    const float* fq   = (const float*)d_in[7];

    char* ws = (char*)d_ws;
    short* lqt = (short*)(ws + OFF_LQT);
    float* x1 = (float*)(ws + OFF_X1);
    float* x2 = (float*)(ws + OFF_X2);
    unsigned* cnt  = (unsigned*)(ws + OFF_CNT);
    unsigned* hist = (unsigned*)(ws + OFF_HIST);

    int W = out_size / (B_ * (TOPK + ENDK));  // 1 + neg_min

    k_zero<<<2048, 256, 0, stream>>>((float4*)hist, cnt);
    k_dense<<<H_ / 4, 256, 0, stream>>>(q, dw, db, x1, 1);
    k_dense<<<H_ / 4, 256, 0, stream>>>(x1, ow, ob, x2, 0);
    k_norm<<<B_, 64, 0, stream>>>(x2, lqt);
    k_gemm_hist<<<K_ / 32, 256, 0, stream>>>(fq, lqt, labels, lblq, hist);
    k_count1<<<64, 256, 0, stream>>>(lblq, cnt);
    k_posmin<<<1, 64, 0, stream>>>(labels, cnt, cnt + 1);
    k_scan<<<64, 1024, 0, stream>>>(hist);

    dim3 gb(B_, (unsigned)((W - 1 + 1023) / 1024));
    k_out<<<gb, 1024, 0, stream>>>(hist, cnt + 1, (float*)d_out, W);
}